// Round 11
// baseline (133.456 us; speedup 1.0000x reference)
//
#include <hip/hip_runtime.h>
#include <hip/hip_bf16.h>

// Problem constants
#define BB 16
#define TT 2048
#define CC 128
#define HH 128
#define NQT128 16          // q tiles of 128 rows

typedef __bf16 bf16x8 __attribute__((ext_vector_type(8)));
typedef __bf16 bf16x4 __attribute__((ext_vector_type(4)));
typedef float  f32x4  __attribute__((ext_vector_type(4)));
typedef unsigned int u32x2 __attribute__((ext_vector_type(2)));

// ws layout (bf16 elems unless noted):
//   Qs  [b][tt16 128][ks 4][lane 64][j 8]   (exp2-domain scale folded)
//   Ks  [b][tt16 128][ks 4][lane 64][j 8]   (32-key tile = 8 KB contig)
//   Vs  [b][t32 64][h16 8][lane 64][j 8]    (32-key tile = 8 KB contig)
//   Wbf 3*128*128 FRAGMENT-SWIZZLED: [which][blk16 8][ks 4][lane 64][j 8]
#define BTH       ((size_t)BB * TT * HH)
#define WBF_OFF   (3 * BTH)

static __device__ __forceinline__ bf16x8 load_cvt8(const float* p) {
    float4 a = *(const float4*)p;
    float4 b = *(const float4*)(p + 4);
    bf16x8 r;
    r[0] = (__bf16)a.x; r[1] = (__bf16)a.y; r[2] = (__bf16)a.z; r[3] = (__bf16)a.w;
    r[4] = (__bf16)b.x; r[5] = (__bf16)b.y; r[6] = (__bf16)b.z; r[7] = (__bf16)b.w;
    return r;
}

// async global->LDS, 16 B/lane: data lands at lds_base + lane*16
static __device__ __forceinline__ void load_lds16(const void* g, void* l) {
    __builtin_amdgcn_global_load_lds(
        (const __attribute__((address_space(1))) unsigned int*)g,
        (__attribute__((address_space(3))) unsigned int*)l, 16, 0, 0);
}

// ---------------------------------------------------------------------------
// W pre-convert + FRAGMENT SWIZZLE (proj W loads become lane*16B coalesced).
// ---------------------------------------------------------------------------
__global__ __launch_bounds__(256) void wcvt_kernel(
    const float* __restrict__ Wq, const float* __restrict__ Wk,
    const float* __restrict__ Wv, __bf16* __restrict__ wbf)
{
    int idx = blockIdx.x * 256 + threadIdx.x;          // < 6144
    int which = idx >> 11;
    int rem = idx & 2047;
    int blk = rem >> 8;
    int r2  = rem & 255;
    int ks   = r2 >> 6;
    int lane = r2 & 63;
    int quad = lane >> 4, l16 = lane & 15;
    const float* src = (which == 0) ? Wq : (which == 1) ? Wk : Wv;
    float sc = (which == 0) ? (0.08838834764831845f * 1.4426950408889634f) : 1.0f;
    const float* p = src + (size_t)(blk * 16 + l16) * CC + ks * 32 + quad * 8;
    bf16x8 v;
    #pragma unroll
    for (int j = 0; j < 8; ++j) v[j] = (__bf16)(p[j] * sc);
    *(bf16x8*)(wbf + (size_t)which * 16384 + (((size_t)(blk * 4 + ks)) << 9) + lane * 8) = v;
}

// ---------------------------------------------------------------------------
// Projection, fully coalesced (x via padded LDS, W fragment-swizzled).
// ---------------------------------------------------------------------------
#define TR_QK 132
#define TR_V  68

__global__ __launch_bounds__(256) void proj_kernel(
    const float* __restrict__ x, __bf16* __restrict__ ws)
{
    __shared__ float  xs[64 * 132];
    __shared__ __bf16 tr[128 * TR_V];

    const int lane = threadIdx.x & 63;
    const int wave = threadIdx.x >> 6;
    const int quad = lane >> 4;
    const int l16  = lane & 15;
    const int tid  = threadIdx.x;
    const int m0 = blockIdx.x * 64;
    const int b  = m0 / TT;
    const int t0 = m0 % TT;

    const __bf16* Wbf = ws + WBF_OFF;
    __bf16* Qs = ws;
    __bf16* Ks = ws + BTH;
    __bf16* Vs = ws + 2 * BTH;

    const float* xg = x + (size_t)m0 * CC;
    #pragma unroll
    for (int t = 0; t < 8; ++t) {
        int f = t * 256 + tid;
        int row = f >> 5, c4 = f & 31;
        float4 v = *(const float4*)(xg + (size_t)f * 4);
        *(float4*)(&xs[row * 132 + c4 * 4]) = v;
    }
    __syncthreads();

    bf16x8 xf[4];
    #pragma unroll
    for (int ks = 0; ks < 4; ++ks)
        xf[ks] = load_cvt8(&xs[(wave * 16 + l16) * 132 + ks * 32 + quad * 8]);

    #pragma unroll
    for (int which = 0; which < 2; ++which) {
        const __bf16* Wb = Wbf + (size_t)which * 16384;
        __bf16* dst = which ? Ks : Qs;
        #pragma unroll
        for (int nt = 0; nt < 8; ++nt) {
            f32x4 acc = {0.f, 0.f, 0.f, 0.f};
            #pragma unroll
            for (int ks = 0; ks < 4; ++ks) {
                bf16x8 wf = *(const bf16x8*)(Wb + (((size_t)(nt * 4 + ks)) << 9) + lane * 8);
                acc = __builtin_amdgcn_mfma_f32_16x16x32_bf16(xf[ks], wf, acc, 0, 0, 0);
            }
            #pragma unroll
            for (int r = 0; r < 4; ++r)
                tr[(wave * 16 + quad * 4 + r) * TR_QK + nt * 16 + l16] = (__bf16)acc[r];
        }
        asm volatile("s_waitcnt lgkmcnt(0)" ::: "memory");
        #pragma unroll
        for (int ks = 0; ks < 4; ++ks) {
            const __bf16* p = &tr[(wave * 16 + l16) * TR_QK + ks * 32 + quad * 8];
            uint2 lo = *(const uint2*)p;
            uint2 hi = *(const uint2*)(p + 4);
            uint4 v; v.x = lo.x; v.y = lo.y; v.z = hi.x; v.w = hi.y;
            __bf16* o = dst + (((size_t)(b * 128 + t0 / 16 + wave) * 4 + ks) << 9) + lane * 8;
            *(uint4*)o = v;
        }
        asm volatile("s_waitcnt lgkmcnt(0)" ::: "memory");
    }

    __syncthreads();
    const __bf16* Wv = Wbf + 2 * 16384;
    #pragma unroll
    for (int msub = 0; msub < 8; ++msub) {
        f32x4 acc = {0.f, 0.f, 0.f, 0.f};
        #pragma unroll
        for (int ks = 0; ks < 4; ++ks) {
            bf16x8 wf = *(const bf16x8*)(Wv + (((size_t)(msub * 4 + ks)) << 9) + lane * 8);
            acc = __builtin_amdgcn_mfma_f32_16x16x32_bf16(wf, xf[ks], acc, 0, 0, 0);
        }
        #pragma unroll
        for (int r = 0; r < 4; ++r)
            tr[(msub * 16 + quad * 4 + r) * TR_V + wave * 16 + l16] = (__bf16)acc[r];
    }
    __syncthreads();
    #pragma unroll
    for (int i = 0; i < 4; ++i) {
        int t32 = i >> 1;
        int h16 = wave * 2 + (i & 1);
        const __bf16* p = &tr[(h16 * 16 + l16) * TR_V + t32 * 32 + quad * 8];
        uint2 lo = *(const uint2*)p;
        uint2 hi = *(const uint2*)(p + 4);
        uint4 v; v.x = lo.x; v.y = lo.y; v.z = hi.x; v.w = hi.y;
        __bf16* o = Vs + (((size_t)(b * 64 + t0 / 32 + t32) * 8 + h16) << 9) + lane * 8;
        *(uint4*)o = v;
    }
}

// ---------------------------------------------------------------------------
// Flash attention, 2-wave blocks, 64-KEY BARRIER INTERVALS, dynamic refill.
// Round-10 cross-check: per-32-key-tile block cost is ~1750cy across BOTH the
// split-K and no-split structures -> the schedule isn't the lever, per-tile
// fixed overhead is. This round:
//  - 64-key tiles: 2x compute work (16 QK + 16 PV MFMA, 32 exp2) against the
//    SAME fixed costs (2 barriers, 1 vmcnt wait, stage issue, loop carry).
//  - LDS 2 x 32KB = 64KB -> 2 blocks/CU resident; grid stays 1024 ->
//    512 resident + 512 BACKFILL with heavy-first order = dynamic balance
//    (round 10 had exactly-resident grid -> imbalance baked in, occ decay).
//  - wave0 stages K (16KB), wave1 stages V; counted vmcnt(16), never drained
//    mid-loop; two-barrier loop (round-3/10 proven race-free pattern).
//  - swapped QK^T (mfma(K,Q) -> S^T); P redistribution in-register via
//    permlane32_swap + permlane16_swap. QK computed once per output.
//  - no forced waves/EU cap (round-2 spill lesson); no device fences (r5).
// ---------------------------------------------------------------------------
__global__ __launch_bounds__(128) void attn_kernel(
    const __bf16* __restrict__ ws, float* __restrict__ outp)
{
    __shared__ char ldsBuf[2][32768];   // per buffer: K 16KB @0, V 16KB @16384

    const int lane = threadIdx.x & 63;
    const int wave = threadIdx.x >> 6;                 // 0..1
    const int quad = lane >> 4;
    const int l16  = lane & 15;
    const int lane8 = lane * 8;
    const int lo16 = lane * 16;

    const int lin = blockIdx.x;                        // 1024 blocks
    const int b   = (lin & 7) * 2 + ((lin >> 3) & 1);  // XCD-clustered batch
    const int kq  = 63 - (lin >> 4);                   // heavy chains first
    const int qw  = kq * 32 + wave * 16;               // wave's 16 q rows
    const int nt  = kq + 1;                            // causal 32-key tiles
    const int nj  = (nt + 1) >> 1;                     // 64-key intervals

    const __bf16* Qs = ws;
    const __bf16* Ks = ws + BTH;
    const __bf16* Vs = ws + 2 * BTH;

    // Q fragments (row16 block = 2*kq + wave)
    bf16x8 qf[4];
    #pragma unroll
    for (int ks = 0; ks < 4; ++ks)
        qf[ks] = *(const bf16x8*)(Qs + (((size_t)(b * 128 + 2 * kq + wave) * 4 + ks) << 9) + lane8);

    float l_r = 0.f;
    f32x4 o[8];
    #pragma unroll
    for (int h8 = 0; h8 < 8; ++h8) o[h8] = (f32x4){0.f, 0.f, 0.f, 0.f};

    // staging: wave0 streams K, wave1 streams V (16 x 1KB chunks per 64 keys)
    const char* sbase = (wave ? (const char*)Vs : (const char*)Ks)
                        + (size_t)b * 524288 + lo16;

    #define STAGE(Jv, BUF)                                         \
        do {                                                       \
            const char* s_ = sbase + ((size_t)(Jv) << 14);         \
            char* d_ = ldsBuf[BUF] + wave * 16384;                 \
            _Pragma("unroll")                                      \
            for (int c_ = 0; c_ < 16; ++c_)                        \
                load_lds16(s_ + c_ * 1024, d_ + c_ * 1024);        \
        } while (0)

    STAGE(0, 0);

    for (int j = 0; j < nj; ++j) {
        const int cur = j & 1;
        // issue next-interval DMA, then counted wait: only stage(j) must land
        if (j + 1 < nj) {
            STAGE(j + 1, cur ^ 1);
            asm volatile("s_waitcnt vmcnt(16)" ::: "memory");
        } else {
            asm volatile("s_waitcnt vmcnt(0)" ::: "memory");
        }
        __builtin_amdgcn_s_barrier();      // stage(j) visible to both waves

        #pragma unroll
        for (int half = 0; half < 2; ++half) {
            const int tt = 2 * j + half;
            if (tt >= nt) continue;                    // uniform per block
            const char* lk = ldsBuf[cur] + half * 8192;
            const char* lv = ldsBuf[cur] + 16384 + half * 8192;

            // ---- S^T = K Q^T (lane holds 4 consecutive keys, q-row l16) ---
            f32x4 s2[2];
            #pragma unroll
            for (int nsub = 0; nsub < 2; ++nsub) {
                bf16x8 kfr[4];
                #pragma unroll
                for (int ks = 0; ks < 4; ++ks)
                    kfr[ks] = *(const bf16x8*)(lk + ((nsub * 4 + ks) << 10) + lo16);
                f32x4 a2 = {0.f, 0.f, 0.f, 0.f};
                __builtin_amdgcn_s_setprio(1);
                #pragma unroll
                for (int ks = 0; ks < 4; ++ks)
                    a2 = __builtin_amdgcn_mfma_f32_16x16x32_bf16(kfr[ks], qf[ks], a2, 0, 0, 0);
                __builtin_amdgcn_s_setprio(0);
                s2[nsub] = a2;
            }

            const int k0 = tt * 32;
            // ---- mask (last tile only) + exp2 + lane-local l; pack P ------
            unsigned int du[2][2];
            if (tt == nt - 1) {                        // boundary tile (uniform)
                const int qrow = qw + l16;
                #pragma unroll
                for (int nsub = 0; nsub < 2; ++nsub) {
                    const int kb = k0 + nsub * 16 + quad * 4;
                    union { bf16x4 v; unsigned int u[2]; } cv;
                    #pragma unroll
                    for (int r = 0; r < 4; ++r) {
                        float sv = (kb + r > qrow) ? -3e38f : s2[nsub][r];
                        float p = __builtin_amdgcn_exp2f(sv);
                        l_r += p;
                        cv.v[r] = (__bf16)p;
                    }
                    du[nsub][0] = cv.u[0];
                    du[nsub][1] = cv.u[1];
                }
            } else {
                #pragma unroll
                for (int nsub = 0; nsub < 2; ++nsub) {
                    union { bf16x4 v; unsigned int u[2]; } cv;
                    #pragma unroll
                    for (int r = 0; r < 4; ++r) {
                        float p = __builtin_amdgcn_exp2f(s2[nsub][r]);
                        l_r += p;
                        cv.v[r] = (__bf16)p;
                    }
                    du[nsub][0] = cv.u[0];
                    du[nsub][1] = cv.u[1];
                }
            }

            // ---- P: C-layout -> A-layout fully in-register ----------------
            bf16x8 pf;
            {
                union { unsigned int u[4]; bf16x8 v; } cc;
                #pragma unroll
                for (int h = 0; h < 2; ++h) {
                    u32x2 t1 = __builtin_amdgcn_permlane32_swap(
                        du[0][h], du[1][h], false, false);
                    u32x2 t2 = __builtin_amdgcn_permlane16_swap(
                        t1[0], t1[1], false, false);
                    cc.u[h]     = t2[0];
                    cc.u[2 + h] = t2[1];
                }
                pf = cc.v;
            }

            // ---- O += P V (k = 32) over all 8 h16 columns -----------------
            __builtin_amdgcn_s_setprio(1);
            #pragma unroll
            for (int h8 = 0; h8 < 8; ++h8) {
                bf16x8 v0 = *(const bf16x8*)(lv + (h8 << 10) + lo16);
                o[h8] = __builtin_amdgcn_mfma_f32_16x16x32_bf16(pf, v0, o[h8], 0, 0, 0);
            }
            __builtin_amdgcn_s_setprio(0);
        }

        // both waves' LDS reads of buf cur retired before it is restaged
        asm volatile("s_waitcnt lgkmcnt(0)" ::: "memory");
        __builtin_amdgcn_s_barrier();
    }
    #undef STAGE

    // ---- normalize + direct write (per-wave) ------------------------------
    l_r += __shfl_xor(l_r, 16, 64);
    l_r += __shfl_xor(l_r, 32, 64);
    float inv[4];
    #pragma unroll
    for (int r = 0; r < 4; ++r)
        inv[r] = 1.0f / __shfl(l_r, (lane & 48) | (quad * 4 + r), 64);
    #pragma unroll
    for (int h8 = 0; h8 < 8; ++h8)
        #pragma unroll
        for (int r = 0; r < 4; ++r)
            outp[(size_t)(b * TT + qw + quad * 4 + r) * HH + h8 * 16 + l16] = o[h8][r] * inv[r];
}

extern "C" void kernel_launch(void* const* d_in, const int* in_sizes, int n_in,
                              void* d_out, int out_size, void* d_ws, size_t ws_size,
                              hipStream_t stream)
{
    const float* x  = (const float*)d_in[0];
    const float* Wq = (const float*)d_in[1];
    const float* Wk = (const float*)d_in[2];
    const float* Wv = (const float*)d_in[3];
    __bf16* ws = (__bf16*)d_ws;
    float* out = (float*)d_out;

    wcvt_kernel<<<24, 256, 0, stream>>>(Wq, Wk, Wv, ws + WBF_OFF);
    proj_kernel<<<512, 256, 0, stream>>>(x, ws);
    attn_kernel<<<1024, 128, 0, stream>>>(ws, out);
}